// Round 18
// baseline (102.437 us; speedup 1.0000x reference)
//
#include <hip/hip_runtime.h>
#include <math.h>

#define NB 32
#define NT 4096
#define ND 512
#define NA 64
#define ND4 (ND / 4)            // 128 float4 units per x-row
#define RPB 128                 // rows per block: 4 waves x 32 rows
#define NBLK (NB * NT / RPB)    // 1024 blocks
#define NPW (NT / RPB)          // 32 block-partials per batch row

typedef __attribute__((ext_vector_type(8))) short short8;   // 8 bf16
typedef __attribute__((ext_vector_type(4))) float f32x4;    // MFMA acc

// ---- split-bf16 via HW packer: f = hi(RNE bf16) + lo(RNE bf16 of resid) ----
__device__ __forceinline__ uint cvtpk(float f0, float f1) {
    uint r;
    asm("v_cvt_pk_bf16_f32 %0, %1, %2" : "=v"(r) : "v"(f0), "v"(f1));
    return r;
}
__device__ __forceinline__ void split2(float f0, float f1, uint& hw, uint& lw) {
    hw = cvtpk(f0, f1);
    float r0 = f0 - __uint_as_float(hw << 16);
    float r1 = f1 - __uint_as_float(hw & 0xffff0000u);
    lw = cvtpk(r0, r1);
}
__device__ __forceinline__ void split8(float4 a, float4 b, short8& hi, short8& lo) {
    union U { short8 s; uint u[4]; } H, L;
    split2(a.x, a.y, H.u[0], L.u[0]);
    split2(a.z, a.w, H.u[1], L.u[1]);
    split2(b.x, b.y, H.u[2], L.u[2]);
    split2(b.z, b.w, H.u[3], L.u[3]);
    hi = H.s; lo = L.s;
}

// ---- fast tanh: (e^{2z}-1)/(e^{2z}+1), z clamped to +-15 (no inf/NaN) ----
__device__ __forceinline__ float fast_tanh(float z) {
    z = fminf(fmaxf(z, -15.f), 15.f);
    float t = __expf(2.f * z);
    return (t - 1.f) * __builtin_amdgcn_rcpf(t + 1.f);
}

// ------------------------------------------------------------------ prep ----
// Pack W1 into MFMA B-fragments (hi/lo bf16), fidx == global thread id.
__global__ __launch_bounds__(256) void k_prep(
    const float* __restrict__ W1, short8* __restrict__ whi, short8* __restrict__ wlo)
{
    int t = blockIdx.x * 256 + threadIdx.x;       // 0..4095
    int l  = t & 63;
    int nt = (t >> 6) & 3;
    int ks = t >> 8;
    int a  = nt * 16 + (l & 15);
    int kb = ks * 32 + (l >> 4) * 8;
    const float* p = W1 + a * ND + kb;
    float4 u = *(const float4*)p;
    float4 v = *(const float4*)(p + 4);
    short8 hi, lo;
    split8(u, v, hi, lo);
    whi[t] = hi;
    wlo[t] = lo;
}

// ----------------------------------------------------------------- fused ----
// R17 (96 us total) + two levers:
// 1. 1-deep register PREFETCH in phase A (T14): next-ks x-loads issued as
//    NAMED variables (rule #20) before computing current ks; branch-free
//    wrap (ks+1)&15. Pins allocator with waves_per_eu(4,4) (= the
//    grid-imposed 4 waves/SIMD) so the ~110-reg live set gets the full
//    128 budget instead of R16's 64-and-spill pathology.
// 2. Max-free softmax retained (|s| <= ||w2||_1 ~ 6.5, no fp32 overflow).
__global__ void __launch_bounds__(256)
__attribute__((amdgpu_waves_per_eu(4, 4)))
k_fused(
    const float* __restrict__ x, const int* __restrict__ mask,
    const short8* __restrict__ whi, const short8* __restrict__ wlo,
    const float* __restrict__ b1, const float* __restrict__ w2,
    float* __restrict__ escore, float* __restrict__ pctx, float* __restrict__ pden)
{
    __shared__ float ctxl[4][ND];      // 8 KB
    __shared__ float wlx[4];

    const int tid = threadIdx.x;
    const int wv  = tid >> 6;
    const int l   = tid & 63;
    const int lr  = l & 15;
    const int lq  = l >> 4;
    const size_t row0 = (size_t)blockIdx.x * RPB + (size_t)wv * 32;

    const float4* __restrict__ x4 = reinterpret_cast<const float4*>(x);
    const float* xb0 = x + (row0 + lr) * ND + lq * 8;        // mt=0 rows
    const float* xb1 = xb0 + 16 * ND;                        // mt=1 rows

    float w2v[4], b1v[4];
#pragma unroll
    for (int nt = 0; nt < 4; ++nt) {
        w2v[nt] = w2[nt * 16 + lr];
        b1v[nt] = b1[nt * 16 + lr];
    }

    // ---- phase A: MFMA scores, 1-deep x prefetch pipeline
    f32x4 acc[2][4];
#pragma unroll
    for (int mt = 0; mt < 2; ++mt)
#pragma unroll
        for (int nt = 0; nt < 4; ++nt) acc[mt][nt] = (f32x4)0.f;

    float4 cu0 = *(const float4*)(xb0);
    float4 cv0 = *(const float4*)(xb0 + 4);
    float4 cu1 = *(const float4*)(xb1);
    float4 cv1 = *(const float4*)(xb1 + 4);

#pragma unroll 1
    for (int ks = 0; ks < 16; ++ks) {
        // issue next chunk's loads FIRST (latency hides under split+MFMA);
        // (ks+1)&15 wraps to a valid in-bounds address on the last iter.
        const int kn = ((ks + 1) & 15) * 32;
        float4 nu0 = *(const float4*)(xb0 + kn);
        float4 nv0 = *(const float4*)(xb0 + kn + 4);
        float4 nu1 = *(const float4*)(xb1 + kn);
        float4 nv1 = *(const float4*)(xb1 + kn + 4);

        short8 ahi0, alo0, ahi1, alo1;
        split8(cu0, cv0, ahi0, alo0);
        split8(cu1, cv1, ahi1, alo1);
#pragma unroll
        for (int nt = 0; nt < 4; ++nt) {
            short8 bh = whi[(ks * 4 + nt) * 64 + l];
            short8 bl = wlo[(ks * 4 + nt) * 64 + l];
            acc[0][nt] = __builtin_amdgcn_mfma_f32_16x16x32_bf16(ahi0, bh, acc[0][nt], 0, 0, 0);
            acc[0][nt] = __builtin_amdgcn_mfma_f32_16x16x32_bf16(ahi0, bl, acc[0][nt], 0, 0, 0);
            acc[0][nt] = __builtin_amdgcn_mfma_f32_16x16x32_bf16(alo0, bh, acc[0][nt], 0, 0, 0);
            acc[1][nt] = __builtin_amdgcn_mfma_f32_16x16x32_bf16(ahi1, bh, acc[1][nt], 0, 0, 0);
            acc[1][nt] = __builtin_amdgcn_mfma_f32_16x16x32_bf16(ahi1, bl, acc[1][nt], 0, 0, 0);
            acc[1][nt] = __builtin_amdgcn_mfma_f32_16x16x32_bf16(alo1, bh, acc[1][nt], 0, 0, 0);
        }
        cu0 = nu0; cv0 = nv0; cu1 = nu1; cv1 = nv1;
    }

    // ---- epilogue (both tiles): score -> e = exp(s) (masked -> 0)
    float ev[2][4];
#pragma unroll
    for (int mt = 0; mt < 2; ++mt) {
#pragma unroll
        for (int rg = 0; rg < 4; ++rg) {
            float s = 0.f;
#pragma unroll
            for (int nt = 0; nt < 4; ++nt)
                s += w2v[nt] * fast_tanh(acc[mt][nt][rg] + b1v[nt]);
            s += __shfl_xor(s, 1);
            s += __shfl_xor(s, 2);
            s += __shfl_xor(s, 4);
            s += __shfl_xor(s, 8);
            int ridx = mt * 16 + lq * 4 + rg;     // row within wave's 32
            bool valid = (mask[row0 + ridx] != 0);
            float e = valid ? __expf(s) : 0.f;    // max-free; |s| <= ~7
            if (lr == 0) escore[row0 + ridx] = e;
            ev[mt][rg] = e;
        }
    }

    // ---- wave denom partial
    float wl = (ev[0][0] + ev[0][1]) + (ev[0][2] + ev[0][3])
             + (ev[1][0] + ev[1][1]) + (ev[1][2] + ev[1][3]);
    wl += __shfl_xor(wl, 16);
    wl += __shfl_xor(wl, 32);
    if (l == 0) wlx[wv] = wl;

    // ---- phase B: ctx over own 32 rows; rows are L2/L3-hot from phase A
    float4 ca = {0.f, 0.f, 0.f, 0.f}, cb = {0.f, 0.f, 0.f, 0.f};
#pragma unroll
    for (int t = 0; t < 32; ++t) {
        float e = __shfl(ev[t >> 4][t & 3], ((t >> 2) & 3) * 16);
        float4 xa = x4[(row0 + t) * ND4 + l];
        float4 xv = x4[(row0 + t) * ND4 + 64 + l];
        ca.x = fmaf(e, xa.x, ca.x);
        ca.y = fmaf(e, xa.y, ca.y);
        ca.z = fmaf(e, xa.z, ca.z);
        ca.w = fmaf(e, xa.w, ca.w);
        cb.x = fmaf(e, xv.x, cb.x);
        cb.y = fmaf(e, xv.y, cb.y);
        cb.z = fmaf(e, xv.z, cb.z);
        cb.w = fmaf(e, xv.w, cb.w);
    }

    // ---- block combine (absolute values; no rescale)
    *(float4*)&ctxl[wv][4 * l]       = ca;
    *(float4*)&ctxl[wv][256 + 4 * l] = cb;
    __syncthreads();                   // ctxl + wlx ready

    float s0 = (ctxl[0][tid] + ctxl[1][tid]) + (ctxl[2][tid] + ctxl[3][tid]);
    int t2 = tid + 256;
    float s1 = (ctxl[0][t2] + ctxl[1][t2]) + (ctxl[2][t2] + ctxl[3][t2]);
    pctx[(size_t)blockIdx.x * ND + tid] = s0;
    pctx[(size_t)blockIdx.x * ND + t2]  = s1;
    if (tid == 0)
        pden[blockIdx.x] = (wlx[0] + wlx[1]) + (wlx[2] + wlx[3]);
}

// ------------------------------------------------------------------ tail ----
// One kernel replaces k_merge + k_weights (one fewer launch, no serial dep):
// blocks 0..NB-1 do the ctx merge; blocks NB.. do weights, each recomputing
// denom from pden (32 uniform scalar loads -- free).
__global__ __launch_bounds__(256) void k_tail(
    const float* __restrict__ pctx, const float* __restrict__ pden,
    const float* __restrict__ escore,
    float* __restrict__ ctx, float* __restrict__ weights)
{
    int bid = blockIdx.x, tid = threadIdx.x;
    if (bid < NB) {
        int b = bid;
        float denom = 0.f;
        for (int i = 0; i < NPW; ++i) denom += pden[b * NPW + i];
        float inv = 1.f / denom;
        int d0 = 2 * tid;
        float a0 = 0.f, a1 = 0.f;
        for (int i = 0; i < NPW; ++i) {
            a0 += pctx[(size_t)(b * NPW + i) * ND + d0];
            a1 += pctx[(size_t)(b * NPW + i) * ND + d0 + 1];
        }
        ctx[(size_t)b * ND + d0]     = a0 * inv;
        ctx[(size_t)b * ND + d0 + 1] = a1 * inv;
    } else {
        int i = (bid - NB) * 256 + tid;           // over B*T
        int b = i >> 12;                          // / NT
        float denom = 0.f;
        for (int j = 0; j < NPW; ++j) denom += pden[b * NPW + j];
        weights[i] = escore[i] * (1.f / denom);   // masked e==0 -> exactly 0
    }
}

// ------------------------------------------------------------------ launch --
extern "C" void kernel_launch(void* const* d_in, const int* in_sizes, int n_in,
                              void* d_out, int out_size, void* d_ws, size_t ws_size,
                              hipStream_t stream)
{
    const float* x    = (const float*)d_in[0];
    const int*   mask = (const int*)d_in[1];
    const float* W1   = (const float*)d_in[2];
    const float* b1   = (const float*)d_in[3];
    const float* w2   = (const float*)d_in[4];

    float* ctx     = (float*)d_out;                   // B*D
    float* weights = (float*)d_out + NB * ND;         // B*T

    float* ws      = (float*)d_ws;
    float* escore  = ws;                              // B*T            (131072)
    float* pctx    = ws + NB * NT;                    // NBLK*ND        (524288)
    float* pden    = pctx + (size_t)NBLK * ND;        // NBLK           (1024)
    short8* whi    = (short8*)(pden + NBLK);          // 64 KB
    short8* wlo    = whi + 16 * 4 * 64;               // 64 KB

    k_prep<<<16, 256, 0, stream>>>(W1, whi, wlo);
    k_fused<<<NBLK, 256, 0, stream>>>(x, mask, whi, wlo, b1, w2,
                                      escore, pctx, pden);
    k_tail<<<NB + NB * NT / 256, 256, 0, stream>>>(pctx, pden, escore,
                                                   ctx, weights);
}

// Round 19
// 94.473 us; speedup vs baseline: 1.0843x; 1.0843x over previous
//
#include <hip/hip_runtime.h>
#include <math.h>

#define NB 32
#define NT 4096
#define ND 512
#define NA 64
#define ND4 (ND / 4)            // 128 float4 units per x-row
#define RPB 128                 // rows per block: 4 waves x 32 rows
#define NBLK (NB * NT / RPB)    // 1024 blocks
#define NPW (NT / RPB)          // 32 block-partials per batch row

typedef __attribute__((ext_vector_type(8))) short short8;   // 8 bf16
typedef __attribute__((ext_vector_type(4))) float f32x4;    // MFMA acc

// ---- split-bf16 via HW packer: f = hi(RNE bf16) + lo(RNE bf16 of resid) ----
__device__ __forceinline__ uint cvtpk(float f0, float f1) {
    uint r;
    asm("v_cvt_pk_bf16_f32 %0, %1, %2" : "=v"(r) : "v"(f0), "v"(f1));
    return r;
}
__device__ __forceinline__ void split2(float f0, float f1, uint& hw, uint& lw) {
    hw = cvtpk(f0, f1);
    float r0 = f0 - __uint_as_float(hw << 16);
    float r1 = f1 - __uint_as_float(hw & 0xffff0000u);
    lw = cvtpk(r0, r1);
}
__device__ __forceinline__ void split8(float4 a, float4 b, short8& hi, short8& lo) {
    union U { short8 s; uint u[4]; } H, L;
    split2(a.x, a.y, H.u[0], L.u[0]);
    split2(a.z, a.w, H.u[1], L.u[1]);
    split2(b.x, b.y, H.u[2], L.u[2]);
    split2(b.z, b.w, H.u[3], L.u[3]);
    hi = H.s; lo = L.s;
}

// ---- fast tanh: (e^{2z}-1)/(e^{2z}+1), z clamped to +-15 (no inf/NaN) ----
__device__ __forceinline__ float fast_tanh(float z) {
    z = fminf(fmaxf(z, -15.f), 15.f);
    float t = __expf(2.f * z);
    return (t - 1.f) * __builtin_amdgcn_rcpf(t + 1.f);
}

// ------------------------------------------------------------------ prep ----
// Pack W1 into MFMA B-fragments (hi/lo bf16), fidx == global thread id.
__global__ __launch_bounds__(256) void k_prep(
    const float* __restrict__ W1, short8* __restrict__ whi, short8* __restrict__ wlo)
{
    int t = blockIdx.x * 256 + threadIdx.x;       // 0..4095
    int l  = t & 63;
    int nt = (t >> 6) & 3;
    int ks = t >> 8;
    int a  = nt * 16 + (l & 15);
    int kb = ks * 32 + (l >> 4) * 8;
    const float* p = W1 + a * ND + kb;
    float4 u = *(const float4*)p;
    float4 v = *(const float4*)(p + 4);
    short8 hi, lo;
    split8(u, v, hi, lo);
    whi[t] = hi;
    wlo[t] = lo;
}

// ----------------------------------------------------------------- fused ----
// EXACT R17 k_fused (96 us total, best so far). R18 lesson: manual 1-deep
// prefetch + waves_per_eu pin REGRESSED (-6.5 us) -- the compiler's own
// schedule at VGPR 64 already back-to-backs both tiles' loads per ks
// (hardware-queue prefetch via vmcnt); forcing unroll-1 + named prefetch
// constrained it (Common-mistake #5). Do not out-schedule the compiler
// on this structure. Max-free softmax: |s| <= ||w2||_1 ~ 6.5, exp(s)
// cannot overflow fp32.
__global__ __launch_bounds__(256, 4) void k_fused(
    const float* __restrict__ x, const int* __restrict__ mask,
    const short8* __restrict__ whi, const short8* __restrict__ wlo,
    const float* __restrict__ b1, const float* __restrict__ w2,
    float* __restrict__ escore, float* __restrict__ pctx, float* __restrict__ pden)
{
    __shared__ float ctxl[4][ND];      // 8 KB
    __shared__ float wlx[4];

    const int tid = threadIdx.x;
    const int wv  = tid >> 6;
    const int l   = tid & 63;
    const int lr  = l & 15;
    const int lq  = l >> 4;
    const size_t row0 = (size_t)blockIdx.x * RPB + (size_t)wv * 32;

    const float4* __restrict__ x4 = reinterpret_cast<const float4*>(x);
    const float* xb = x + (row0 + lr) * ND + lq * 8;

    float w2v[4], b1v[4];
#pragma unroll
    for (int nt = 0; nt < 4; ++nt) {
        w2v[nt] = w2[nt * 16 + lr];
        b1v[nt] = b1[nt * 16 + lr];
    }

    // ---- phase A: MFMA scores for the wave's 32 rows (2 M-tiles)
    f32x4 acc[2][4];
#pragma unroll
    for (int mt = 0; mt < 2; ++mt)
#pragma unroll
        for (int nt = 0; nt < 4; ++nt) acc[mt][nt] = (f32x4)0.f;

    for (int ks = 0; ks < 16; ++ks) {
        short8 ahi[2], alo[2];
#pragma unroll
        for (int mt = 0; mt < 2; ++mt) {
            const float* p = xb + mt * 16 * ND + ks * 32;
            float4 u = *(const float4*)p;
            float4 v = *(const float4*)(p + 4);
            split8(u, v, ahi[mt], alo[mt]);
        }
#pragma unroll
        for (int nt = 0; nt < 4; ++nt) {
            short8 bh = whi[(ks * 4 + nt) * 64 + l];
            short8 bl = wlo[(ks * 4 + nt) * 64 + l];
#pragma unroll
            for (int mt = 0; mt < 2; ++mt) {
                acc[mt][nt] = __builtin_amdgcn_mfma_f32_16x16x32_bf16(ahi[mt], bh, acc[mt][nt], 0, 0, 0);
                acc[mt][nt] = __builtin_amdgcn_mfma_f32_16x16x32_bf16(ahi[mt], bl, acc[mt][nt], 0, 0, 0);
                acc[mt][nt] = __builtin_amdgcn_mfma_f32_16x16x32_bf16(alo[mt], bh, acc[mt][nt], 0, 0, 0);
            }
        }
    }

    // ---- epilogue (both tiles): score -> e = exp(s) (masked -> 0)
    float ev[2][4];
#pragma unroll
    for (int mt = 0; mt < 2; ++mt) {
#pragma unroll
        for (int rg = 0; rg < 4; ++rg) {
            float s = 0.f;
#pragma unroll
            for (int nt = 0; nt < 4; ++nt)
                s += w2v[nt] * fast_tanh(acc[mt][nt][rg] + b1v[nt]);
            s += __shfl_xor(s, 1);
            s += __shfl_xor(s, 2);
            s += __shfl_xor(s, 4);
            s += __shfl_xor(s, 8);
            int ridx = mt * 16 + lq * 4 + rg;     // row within wave's 32
            bool valid = (mask[row0 + ridx] != 0);
            float e = valid ? __expf(s) : 0.f;    // max-free; |s| <= ~7
            if (lr == 0) escore[row0 + ridx] = e;
            ev[mt][rg] = e;
        }
    }

    // ---- wave denom partial
    float wl = (ev[0][0] + ev[0][1]) + (ev[0][2] + ev[0][3])
             + (ev[1][0] + ev[1][1]) + (ev[1][2] + ev[1][3]);
    wl += __shfl_xor(wl, 16);
    wl += __shfl_xor(wl, 32);
    if (l == 0) wlx[wv] = wl;

    // ---- phase B: ctx over own 32 rows; rows are L2/L3-hot from phase A
    float4 ca = {0.f, 0.f, 0.f, 0.f}, cb = {0.f, 0.f, 0.f, 0.f};
#pragma unroll
    for (int t = 0; t < 32; ++t) {
        float e = __shfl(ev[t >> 4][t & 3], ((t >> 2) & 3) * 16);
        float4 xa = x4[(row0 + t) * ND4 + l];
        float4 xv = x4[(row0 + t) * ND4 + 64 + l];
        ca.x = fmaf(e, xa.x, ca.x);
        ca.y = fmaf(e, xa.y, ca.y);
        ca.z = fmaf(e, xa.z, ca.z);
        ca.w = fmaf(e, xa.w, ca.w);
        cb.x = fmaf(e, xv.x, cb.x);
        cb.y = fmaf(e, xv.y, cb.y);
        cb.z = fmaf(e, xv.z, cb.z);
        cb.w = fmaf(e, xv.w, cb.w);
    }

    // ---- block combine (absolute values; no rescale)
    *(float4*)&ctxl[wv][4 * l]       = ca;
    *(float4*)&ctxl[wv][256 + 4 * l] = cb;
    __syncthreads();                   // ctxl + wlx ready

    float s0 = (ctxl[0][tid] + ctxl[1][tid]) + (ctxl[2][tid] + ctxl[3][tid]);
    int t2 = tid + 256;
    float s1 = (ctxl[0][t2] + ctxl[1][t2]) + (ctxl[2][t2] + ctxl[3][t2]);
    pctx[(size_t)blockIdx.x * ND + tid] = s0;
    pctx[(size_t)blockIdx.x * ND + t2]  = s1;
    if (tid == 0)
        pden[blockIdx.x] = (wlx[0] + wlx[1]) + (wlx[2] + wlx[3]);
}

// ------------------------------------------------------------------ tail ----
// One kernel replaces k_merge + k_weights (one fewer launch, no serial dep):
// blocks 0..NB-1 do the ctx merge; blocks NB.. do weights, each recomputing
// denom from pden (32 uniform scalar loads -- free). Kept from R18 (this
// part was not the regression).
__global__ __launch_bounds__(256) void k_tail(
    const float* __restrict__ pctx, const float* __restrict__ pden,
    const float* __restrict__ escore,
    float* __restrict__ ctx, float* __restrict__ weights)
{
    int bid = blockIdx.x, tid = threadIdx.x;
    if (bid < NB) {
        int b = bid;
        float denom = 0.f;
        for (int i = 0; i < NPW; ++i) denom += pden[b * NPW + i];
        float inv = 1.f / denom;
        int d0 = 2 * tid;
        float a0 = 0.f, a1 = 0.f;
        for (int i = 0; i < NPW; ++i) {
            a0 += pctx[(size_t)(b * NPW + i) * ND + d0];
            a1 += pctx[(size_t)(b * NPW + i) * ND + d0 + 1];
        }
        ctx[(size_t)b * ND + d0]     = a0 * inv;
        ctx[(size_t)b * ND + d0 + 1] = a1 * inv;
    } else {
        int i = (bid - NB) * 256 + tid;           // over B*T
        int b = i >> 12;                          // / NT
        float denom = 0.f;
        for (int j = 0; j < NPW; ++j) denom += pden[b * NPW + j];
        weights[i] = escore[i] * (1.f / denom);   // masked e==0 -> exactly 0
    }
}

// ------------------------------------------------------------------ launch --
extern "C" void kernel_launch(void* const* d_in, const int* in_sizes, int n_in,
                              void* d_out, int out_size, void* d_ws, size_t ws_size,
                              hipStream_t stream)
{
    const float* x    = (const float*)d_in[0];
    const int*   mask = (const int*)d_in[1];
    const float* W1   = (const float*)d_in[2];
    const float* b1   = (const float*)d_in[3];
    const float* w2   = (const float*)d_in[4];

    float* ctx     = (float*)d_out;                   // B*D
    float* weights = (float*)d_out + NB * ND;         // B*T

    float* ws      = (float*)d_ws;
    float* escore  = ws;                              // B*T            (131072)
    float* pctx    = ws + NB * NT;                    // NBLK*ND        (524288)
    float* pden    = pctx + (size_t)NBLK * ND;        // NBLK           (1024)
    short8* whi    = (short8*)(pden + NBLK);          // 64 KB
    short8* wlo    = whi + 16 * 4 * 64;               // 64 KB

    k_prep<<<16, 256, 0, stream>>>(W1, whi, wlo);
    k_fused<<<NBLK, 256, 0, stream>>>(x, mask, whi, wlo, b1, w2,
                                      escore, pctx, pden);
    k_tail<<<NB + NB * NT / 256, 256, 0, stream>>>(pctx, pden, escore,
                                                   ctx, weights);
}